// Round 10
// baseline (11115.627 us; speedup 1.0000x reference)
//
#include <hip/hip_runtime.h>
#include <hip/hip_fp16.h>

#define NP 16384
#define MC 4096
#define R2F 0.04f
#define MAXC 256
#define NBIN 32768

typedef _Float16 f16x8 __attribute__((ext_vector_type(8)));
typedef float f32x4 __attribute__((ext_vector_type(4)));

// Reference-matching squared distance: (dx*dx + dy*dy) + dz*dz, no fma contraction.
__device__ __forceinline__ float sqdist3(float ax, float ay, float az,
                                         float bx, float by, float bz) {
    float dx = ax - bx, dy = ay - by, dz = az - bz;
    return __fadd_rn(__fadd_rn(__fmul_rn(dx, dx), __fmul_rn(dy, dy)), __fmul_rn(dz, dz));
}

__device__ __forceinline__ unsigned morton3(float X, float Y, float Z) {
    int qx = (int)fminf(31.f, fmaxf(0.f, (X + 4.5f) * (31.f / 9.f)));
    int qy = (int)fminf(31.f, fmaxf(0.f, (Y + 4.5f) * (31.f / 9.f)));
    int qz = (int)fminf(31.f, fmaxf(0.f, (Z + 4.5f) * (31.f / 9.f)));
    unsigned mx = (qx & 1) | ((qx & 2) << 2) | ((qx & 4) << 4) | ((qx & 8) << 6) | ((qx & 16) << 8);
    unsigned my = (qy & 1) | ((qy & 2) << 2) | ((qy & 4) << 4) | ((qy & 8) << 6) | ((qy & 16) << 8);
    unsigned mz = (qz & 1) | ((qz & 2) << 2) | ((qz & 4) << 4) | ((qz & 8) << 6) | ((qz & 16) << 8);
    return mx | (my << 1) | (mz << 2);
}

// ---------------- prep: pos4 + transposed f16 weights + zero histogram ----------------
__global__ __launch_bounds__(256) void k_prep(const float* __restrict__ x,
    const float* __restrict__ W1, const float* __restrict__ W2, const float* __restrict__ W3,
    float4* __restrict__ pos4, _Float16* __restrict__ w1t,
    _Float16* __restrict__ w2t, _Float16* __restrict__ w3t, unsigned* __restrict__ hist)
{
    int tid = blockIdx.x * 256 + threadIdx.x;
    if (tid < NP) {
        long b = (long)tid * 131;
        float4 p; p.x = x[b]; p.y = x[b + 1]; p.z = x[b + 2]; p.w = 0.f;
        pos4[tid] = p;
    } else if (tid < NP + 128 * 168) {
        int i = tid - NP; int c = i / 168, k = i % 168;
        w1t[i] = (k < 131) ? (_Float16)W1[k * 128 + c] : (_Float16)0.f;
    } else if (tid < NP + 128 * 168 + 128 * 136) {
        int i = tid - (NP + 128 * 168); int c = i / 136, k = i % 136;
        w2t[i] = (k < 128) ? (_Float16)W2[k * 128 + c] : (_Float16)0.f;
    } else if (tid < NP + 128 * 168 + 128 * 136 + 256 * 136) {
        int i = tid - (NP + 128 * 168 + 128 * 136); int c = i / 136, k = i % 136;
        w3t[i] = (k < 128) ? (_Float16)W3[k * 256 + c] : (_Float16)0.f;
    } else if (tid < NP + 128 * 168 + 128 * 136 + 256 * 136 + NBIN) {
        hist[tid - (NP + 128 * 168 + 128 * 136 + 256 * 136)] = 0u;
    }
}

// ---------------- Morton histogram ----------------
__global__ __launch_bounds__(256) void k_hist(const float* __restrict__ x,
    unsigned* __restrict__ codes, unsigned* __restrict__ hist)
{
    int p = blockIdx.x * 256 + threadIdx.x;
    if (p < NP) {
        long b = (long)p * 131;
        unsigned c = morton3(x[b], x[b + 1], x[b + 2]);
        codes[p] = c;
        atomicAdd(&hist[c], 1u);
    }
}

// ---------------- exclusive prefix over 32768 bins (1 WG) ----------------
__global__ __launch_bounds__(1024) void k_scan(unsigned* __restrict__ hist)
{
    __shared__ unsigned wsum[1024];
    const int t = threadIdx.x;
    const int base = t * 32;
    unsigned loc[32]; unsigned s = 0;
    #pragma unroll
    for (int k = 0; k < 32; k++) loc[k] = hist[base + k];
    #pragma unroll
    for (int k = 0; k < 32; k++) { unsigned v = loc[k]; loc[k] = s; s += v; }
    wsum[t] = s;
    __syncthreads();
    for (int off = 1; off < 1024; off <<= 1) {
        unsigned v = (t >= off) ? wsum[t - off] : 0u;
        __syncthreads();
        if (t >= off) wsum[t] += v;
        __syncthreads();
    }
    unsigned coff = wsum[t] - s;   // exclusive chunk offset
    #pragma unroll
    for (int k = 0; k < 32; k++) hist[base + k] = loc[k] + coff;
}

// ---------------- scatter into Morton order; w carries ~orig_idx ----------------
__global__ __launch_bounds__(256) void k_scatter(const float* __restrict__ x,
    const unsigned* __restrict__ codes, unsigned* __restrict__ hist,
    float4* __restrict__ pos4s)
{
    int p = blockIdx.x * 256 + threadIdx.x;
    if (p < NP) {
        unsigned dst = atomicAdd(&hist[codes[p]], 1u);
        long b = (long)p * 131;
        pos4s[dst] = make_float4(x[b], x[b + 1], x[b + 2], __uint_as_float(~(unsigned)p));
    }
}

// ---------------- FPS: 512 thr (8 waves), 32 sorted pts/thread, exact sphere pruning ----------
// Serial chain per iter: [active-wave update] -> wave butterfly (key+coords payload, skipped
// for waves pruned 2 iters running) -> LDS -> barrier -> 8-entry payload reduce. No global
// load in the chain: winner coords travel with the key.
__global__ __launch_bounds__(512, 2) void k_fps(const float4* __restrict__ pos4s,
                                                const float4* __restrict__ pos4,
                                                float4* __restrict__ centers)
{
    __shared__ unsigned long long s_key[2][8];
    __shared__ float4 s_pos[2][8];
    const int t = threadIdx.x, lane = t & 63, wv = t >> 6;
    float md[32];
    float mnx = 1e30f, mxx = -1e30f, mny = 1e30f, mxy = -1e30f, mnz = 1e30f, mxz = -1e30f;
    #pragma unroll
    for (int i = 0; i < 32; i++) {
        float4 p = pos4s[t * 32 + i];           // contiguous sorted chunk: spatially compact
        md[i] = __builtin_inff();
        mnx = fminf(mnx, p.x); mxx = fmaxf(mxx, p.x);
        mny = fminf(mny, p.y); mxy = fmaxf(mxy, p.y);
        mnz = fminf(mnz, p.z); mxz = fmaxf(mxz, p.z);
    }
    const float bcx = 0.5f * (mnx + mxx), bcy = 0.5f * (mny + mxy), bcz = 0.5f * (mnz + mxz);
    float br2 = 0.f;
    #pragma unroll
    for (int i = 0; i < 32; i++) {
        float4 p = pos4s[t * 32 + i];
        float dx = p.x - bcx, dy = p.y - bcy, dz = p.z - bcz;
        br2 = fmaxf(br2, dx * dx + dy * dy + dz * dz);
    }
    const float br = __builtin_sqrtf(br2) * 1.0001f;   // safe upper bound on chunk radius
    float thr2 = __builtin_inff();                     // (br + 1.0001*sqrt(max md))^2
    unsigned long long kc = 0ull;                      // cached chunk key
    float wx = 0.f, wy = 0.f, wz = 0.f;                // cached chunk-winner coords
    bool prevwact = true;

    float4 c0 = pos4[0];
    float cx = c0.x, cy = c0.y, cz = c0.z;
    if (t == 0) centers[0] = make_float4(cx, cy, cz, 0.f);

    for (int m = 0; m < MC - 1; m++) {
        float ddx = cx - bcx, ddy = cy - bcy, ddz = cz - bcz;
        float D2 = ddx * ddx + ddy * ddy + ddz * ddz;
        // Skip is exact: D2*0.999 >= thr2 proves every d2_ref(p,c) > md[p] (0.1% margin
        // vs <=1e-6 rounding of the bound math), so reference fminf is a no-op and the
        // cached chunk key/coords are unchanged.
        bool act = (D2 * 0.999f < thr2);
        if (act) {
            unsigned long long k = 0ull;
            float nx = 0.f, ny = 0.f, nz = 0.f;
            #pragma unroll
            for (int i = 0; i < 32; i++) {
                float4 p = pos4s[t * 32 + i];   // L2-hot reload, active chunks only
                float d = sqdist3(p.x, p.y, p.z, cx, cy, cz);
                float nmd = fminf(md[i], d);
                md[i] = nmd;
                unsigned long long ki =
                    ((unsigned long long)__float_as_uint(nmd) << 32) |
                    (unsigned long long)__float_as_uint(p.w);   // ~orig_idx bits
                bool gt = ki > k;
                k = gt ? ki : k;
                nx = gt ? p.x : nx; ny = gt ? p.y : ny; nz = gt ? p.z : nz;
            }
            kc = k; wx = nx; wy = ny; wz = nz;
            float lv = __uint_as_float((unsigned)(kc >> 32));
            float tt = br + 1.0001f * __builtin_sqrtf(lv);
            thr2 = tt * tt;
        }
        unsigned long long bal = __ballot(act);
        // Stage-1 butterfly + LDS write only when this wave's reduced value can have
        // changed (active now or last iter); parity slot then still holds the exact value.
        if (bal != 0ull || prevwact) {
            unsigned long long key = kc;
            float x1 = wx, y1 = wy, z1 = wz;
            #pragma unroll
            for (int off = 1; off < 64; off <<= 1) {
                unsigned long long ok = __shfl_xor(key, off);
                float ox = __shfl_xor(x1, off);
                float oy = __shfl_xor(y1, off);
                float oz = __shfl_xor(z1, off);
                bool sw = ok > key;
                key = sw ? ok : key;
                x1 = sw ? ox : x1; y1 = sw ? oy : y1; z1 = sw ? oz : z1;
            }
            if (lane == 0) {
                s_key[m & 1][wv] = key;
                s_pos[m & 1][wv] = make_float4(x1, y1, z1, 0.f);
            }
        }
        prevwact = (bal != 0ull);
        __syncthreads();                        // the ONLY barrier per iteration
        int e = lane & 7;
        unsigned long long key = s_key[m & 1][e];
        float4 pp = s_pos[m & 1][e];
        #pragma unroll
        for (int off = 1; off < 8; off <<= 1) {
            unsigned long long ok = __shfl_xor(key, off);
            float ox = __shfl_xor(pp.x, off);
            float oy = __shfl_xor(pp.y, off);
            float oz = __shfl_xor(pp.z, off);
            bool sw = ok > key;
            key = sw ? ok : key;
            pp.x = sw ? ox : pp.x; pp.y = sw ? oy : pp.y; pp.z = sw ? oz : pp.z;
        }
        cx = pp.x; cy = pp.y; cz = pp.z;
        if (t == 0) centers[m + 1] = make_float4(cx, cy, cz, 0.f);
    }
}

// ---------------- kNN within radius: one wave per center ----------------
__global__ __launch_bounds__(256) void k_knn(const float4* __restrict__ pos4,
                                             const float4* __restrict__ centers,
                                             int* __restrict__ nbr_cnt,
                                             int* __restrict__ nbr_idx)
{
    __shared__ int s_ci[4][MAXC];
    __shared__ float s_cd[4][MAXC];
    const int t = threadIdx.x, lane = t & 63, wv = t >> 6;
    const int m = blockIdx.x * 4 + wv;
    float4 c = centers[m];
    int base = 0;
    for (int ch = 0; ch < NP / 64; ch++) {
        int p = ch * 64 + lane;
        float4 q = pos4[p];
        float d2 = sqdist3(q.x, q.y, q.z, c.x, c.y, c.z);
        bool pred = (d2 <= R2F);
        unsigned long long mk = __ballot(pred);
        if (pred) {
            int slot = base + (int)__popcll(mk & ((1ull << lane) - 1ull));
            if (slot < MAXC) { s_ci[wv][slot] = p; s_cd[wv][slot] = d2; }
        }
        base += (int)__popcll(mk);
    }
    int cc = min(base, MAXC);
    __syncthreads();
    if (cc <= 32) {
        if (lane < cc) nbr_idx[m * 32 + lane] = s_ci[wv][lane];
        if (lane == 0) nbr_cnt[m] = cc;
    } else {
        int ng = (cc + 63) >> 6;
        for (int g = 0; g < ng; g++) {
            int i = g * 64 + lane;
            if (i < cc) {
                float di = s_cd[wv][i]; int pi = s_ci[wv][i];
                int rank = 0;
                for (int j = 0; j < cc; j++) {
                    float dj = s_cd[wv][j]; int pj = s_ci[wv][j];
                    rank += (dj < di || (dj == di && pj < pi)) ? 1 : 0;
                }
                if (rank < 32) nbr_idx[m * 32 + rank] = pi;
            }
        }
        if (lane == 0) nbr_cnt[m] = 32;
    }
}

// ---------------- fused gather + 3-layer MLP (f16 MFMA) + masked maxpool ----------------
__global__ __launch_bounds__(256) void k_mlp(const float* __restrict__ x,
    const float4* __restrict__ pos4, const float4* __restrict__ centers,
    const int* __restrict__ nbr_cnt, const int* __restrict__ nbr_idx,
    const _Float16* __restrict__ w1t, const _Float16* __restrict__ w2t,
    const _Float16* __restrict__ w3t,
    const float* __restrict__ b1, const float* __restrict__ b2, const float* __restrict__ b3,
    float* __restrict__ out)
{
    __shared__ __align__(16) _Float16 sA[64 * 168];    // X tile: feat(128)+rel(3)+pad, K=160 used
    __shared__ __align__(16) _Float16 sW[256 * 136];   // union: W1T(128x168) / W2T(128x136) / W3T(256x136)
    __shared__ __align__(16) _Float16 sH1[64 * 136];
    __shared__ __align__(16) _Float16 sH2[64 * 136];
    __shared__ float s_pool[4][256];
    __shared__ int s_cnt[2];

    const int t = threadIdx.x, lane = t & 63, wv = t >> 6;
    const int bid = blockIdx.x;

    // ---- stage A (gather rows for 2 centers = 64 rows) ----
    {
        int r = t >> 2, tsub = t & 3;
        int g = r >> 5, s = r & 31;
        int m = bid * 2 + g;
        int cnt = nbr_cnt[m];
        if (t < 2) s_cnt[t] = nbr_cnt[bid * 2 + t];
        _Float16* row = &sA[r * 168];
        if (s < cnt) {
            int col = nbr_idx[m * 32 + s];
            const float* fx = x + (long)col * 131 + 3;
            for (int k = tsub * 32; k < tsub * 32 + 32; k++) row[k] = (_Float16)fx[k];
            if (tsub == 0) {
                float4 ctr = centers[m];
                float4 pp = pos4[col];
                row[128] = (_Float16)(pp.x - ctr.x);
                row[129] = (_Float16)(pp.y - ctr.y);
                row[130] = (_Float16)(pp.z - ctr.z);
                for (int k = 131; k < 168; k++) row[k] = (_Float16)0.f;
            }
        } else {
            for (int k = tsub * 32; k < tsub * 32 + 32; k++) row[k] = (_Float16)0.f;
            if (tsub == 0) for (int k = 128; k < 168; k++) row[k] = (_Float16)0.f;
        }
    }
    // copy W1T
    {
        const uint4* src = (const uint4*)w1t; uint4* dst = (uint4*)sW;
        for (int i = t; i < (128 * 168) / 8; i += 256) dst[i] = src[i];
    }
    __syncthreads();

    const int cl = lane & 15;
    const int kgrp = (lane >> 4) * 8;
    const int rsub = (lane >> 4) * 4;
    const int R0 = wv * 16;

    // ---- GEMM1: [64x160] @ W1T -> relu -> sH1 ----
    {
        f32x4 acc[8];
        #pragma unroll
        for (int i = 0; i < 8; i++) acc[i] = (f32x4){0.f, 0.f, 0.f, 0.f};
        #pragma unroll
        for (int ks = 0; ks < 5; ks++) {
            int kb = ks * 32 + kgrp;
            f16x8 a = *(const f16x8*)&sA[(R0 + cl) * 168 + kb];
            #pragma unroll
            for (int ct = 0; ct < 8; ct++) {
                f16x8 b = *(const f16x8*)&sW[(ct * 16 + cl) * 168 + kb];
                acc[ct] = __builtin_amdgcn_mfma_f32_16x16x32_f16(a, b, acc[ct], 0, 0, 0);
            }
        }
        #pragma unroll
        for (int ct = 0; ct < 8; ct++) {
            int c = ct * 16 + cl;
            float bb = b1[c];
            #pragma unroll
            for (int v = 0; v < 4; v++) {
                float val = fmaxf(acc[ct][v] + bb, 0.f);
                sH1[(R0 + rsub + v) * 136 + c] = (_Float16)val;
            }
        }
    }
    __syncthreads();
    // copy W2T
    {
        const uint4* src = (const uint4*)w2t; uint4* dst = (uint4*)sW;
        for (int i = t; i < (128 * 136) / 8; i += 256) dst[i] = src[i];
    }
    __syncthreads();
    // ---- GEMM2: [64x128] @ W2T -> relu -> sH2 ----
    {
        f32x4 acc[8];
        #pragma unroll
        for (int i = 0; i < 8; i++) acc[i] = (f32x4){0.f, 0.f, 0.f, 0.f};
        #pragma unroll
        for (int ks = 0; ks < 4; ks++) {
            int kb = ks * 32 + kgrp;
            f16x8 a = *(const f16x8*)&sH1[(R0 + cl) * 136 + kb];
            #pragma unroll
            for (int ct = 0; ct < 8; ct++) {
                f16x8 b = *(const f16x8*)&sW[(ct * 16 + cl) * 136 + kb];
                acc[ct] = __builtin_amdgcn_mfma_f32_16x16x32_f16(a, b, acc[ct], 0, 0, 0);
            }
        }
        #pragma unroll
        for (int ct = 0; ct < 8; ct++) {
            int c = ct * 16 + cl;
            float bb = b2[c];
            #pragma unroll
            for (int v = 0; v < 4; v++) {
                float val = fmaxf(acc[ct][v] + bb, 0.f);
                sH2[(R0 + rsub + v) * 136 + c] = (_Float16)val;
            }
        }
    }
    __syncthreads();
    // copy W3T
    {
        const uint4* src = (const uint4*)w3t; uint4* dst = (uint4*)sW;
        for (int i = t; i < (256 * 136) / 8; i += 256) dst[i] = src[i];
    }
    __syncthreads();
    // ---- GEMM3: [64x128] @ W3T (N=256) -> relu -> masked maxpool ----
    {
        f32x4 acc[16];
        #pragma unroll
        for (int i = 0; i < 16; i++) acc[i] = (f32x4){0.f, 0.f, 0.f, 0.f};
        #pragma unroll
        for (int ks = 0; ks < 4; ks++) {
            int kb = ks * 32 + kgrp;
            f16x8 a = *(const f16x8*)&sH2[(R0 + cl) * 136 + kb];
            #pragma unroll
            for (int ct = 0; ct < 16; ct++) {
                f16x8 b = *(const f16x8*)&sW[(ct * 16 + cl) * 136 + kb];
                acc[ct] = __builtin_amdgcn_mfma_f32_16x16x32_f16(a, b, acc[ct], 0, 0, 0);
            }
        }
        int cnt = s_cnt[wv >> 1];
        #pragma unroll
        for (int ct = 0; ct < 16; ct++) {
            int c = ct * 16 + cl;
            float bb = b3[c];
            float p = -__builtin_inff();
            #pragma unroll
            for (int v = 0; v < 4; v++) {
                int srow = (wv & 1) * 16 + rsub + v;   // slot within center [0,32)
                float val = fmaxf(acc[ct][v] + bb, 0.f);
                if (srow < cnt) p = fmaxf(p, val);
            }
            p = fmaxf(p, __shfl_xor(p, 16));
            p = fmaxf(p, __shfl_xor(p, 32));
            if (lane < 16) s_pool[wv][ct * 16 + lane] = p;
        }
    }
    __syncthreads();
    {
        float p0 = fmaxf(s_pool[0][t], s_pool[1][t]);
        float p1 = fmaxf(s_pool[2][t], s_pool[3][t]);
        out[(bid * 2 + 0) * 256 + t] = p0;
        out[(bid * 2 + 1) * 256 + t] = p1;
    }
}

extern "C" void kernel_launch(void* const* d_in, const int* in_sizes, int n_in,
                              void* d_out, int out_size, void* d_ws, size_t ws_size,
                              hipStream_t stream)
{
    const float* x  = (const float*)d_in[0];
    const float* W1 = (const float*)d_in[1];
    const float* b1 = (const float*)d_in[2];
    const float* W2 = (const float*)d_in[3];
    const float* b2 = (const float*)d_in[4];
    const float* W3 = (const float*)d_in[5];
    const float* b3 = (const float*)d_in[6];
    float* out = (float*)d_out;

    char* w = (char*)d_ws;
    float4* pos4    = (float4*)(w + 0);          // 262144 B
    float4* centers = (float4*)(w + 262144);     // 65536 B
    int* nbr_cnt    = (int*)(w + 327680);        // 16384 B
    int* nbr_idx    = (int*)(w + 344064);        // 524288 B
    _Float16* w1t   = (_Float16*)(w + 868352);   // 43008 B
    _Float16* w2t   = (_Float16*)(w + 911360);   // 34816 B
    _Float16* w3t   = (_Float16*)(w + 946176);   // 69632 B
    float4* pos4s   = (float4*)(w + 1015808);    // 262144 B
    unsigned* codes = (unsigned*)(w + 1277952);  // 65536 B
    unsigned* hist  = (unsigned*)(w + 1343488);  // 131072 B -> end 1474560 B

    k_prep<<<480, 256, 0, stream>>>(x, W1, W2, W3, pos4, w1t, w2t, w3t, hist);
    k_hist<<<64, 256, 0, stream>>>(x, codes, hist);
    k_scan<<<1, 1024, 0, stream>>>(hist);
    k_scatter<<<64, 256, 0, stream>>>(x, codes, hist, pos4s);
    k_fps<<<1, 512, 0, stream>>>(pos4s, pos4, centers);
    k_knn<<<1024, 256, 0, stream>>>(pos4, centers, nbr_cnt, nbr_idx);
    k_mlp<<<2048, 256, 0, stream>>>(x, pos4, centers, nbr_cnt, nbr_idx,
                                    w1t, w2t, w3t, b1, b2, b3, out);
}

// Round 14
// 7280.062 us; speedup vs baseline: 1.5269x; 1.5269x over previous
//
#include <hip/hip_runtime.h>
#include <hip/hip_fp16.h>

#define NP 16384
#define MC 4096
#define R2F 0.04f
#define MAXC 256

typedef _Float16 f16x8 __attribute__((ext_vector_type(8)));
typedef float f32x4 __attribute__((ext_vector_type(4)));

// Reference-matching squared distance: (dx*dx + dy*dy) + dz*dz, no fma contraction.
__device__ __forceinline__ float sqdist3(float ax, float ay, float az,
                                         float bx, float by, float bz) {
    float dx = ax - bx, dy = ay - by, dz = az - bz;
    return __fadd_rn(__fadd_rn(__fmul_rn(dx, dx), __fmul_rn(dy, dy)), __fmul_rn(dz, dz));
}

// ---------------- prep: pos4 + transposed f16 weights ----------------
__global__ __launch_bounds__(256) void k_prep(const float* __restrict__ x,
    const float* __restrict__ W1, const float* __restrict__ W2, const float* __restrict__ W3,
    float4* __restrict__ pos4, _Float16* __restrict__ w1t,
    _Float16* __restrict__ w2t, _Float16* __restrict__ w3t)
{
    int tid = blockIdx.x * 256 + threadIdx.x;
    if (tid < NP) {
        long b = (long)tid * 131;
        float4 p; p.x = x[b]; p.y = x[b + 1]; p.z = x[b + 2]; p.w = 0.f;
        pos4[tid] = p;
    } else if (tid < NP + 128 * 168) {
        int i = tid - NP; int c = i / 168, k = i % 168;
        w1t[i] = (k < 131) ? (_Float16)W1[k * 128 + c] : (_Float16)0.f;
    } else if (tid < NP + 128 * 168 + 128 * 136) {
        int i = tid - (NP + 128 * 168); int c = i / 136, k = i % 136;
        w2t[i] = (k < 128) ? (_Float16)W2[k * 128 + c] : (_Float16)0.f;
    } else if (tid < NP + 128 * 168 + 128 * 136 + 256 * 136) {
        int i = tid - (NP + 128 * 168 + 128 * 136); int c = i / 136, k = i % 136;
        w3t[i] = (k < 128) ? (_Float16)W3[k * 256 + c] : (_Float16)0.f;
    }
}

// ---------------- FPS: round-3 structure, spill fixed via (512,2) ----------------
// 512 thr / 8 waves; thread owns pts {i*512+t} with px/py/pz/md ALL in registers
// ((512,2) -> 256-VGPR cap; ~150 live regs, no scratch). One barrier per iter,
// packed u64 key (md bits | ~idx) max-reduce, broadcast pos4[idx] center load.
__global__ __launch_bounds__(512, 2) void k_fps(const float4* __restrict__ pos4,
                                                float4* __restrict__ centers)
{
    __shared__ unsigned long long s_key[2][8];
    const int t = threadIdx.x;
    const int lane = t & 63;
    const int wv = t >> 6;
    float px[32], py[32], pz[32], md[32];
    #pragma unroll
    for (int i = 0; i < 32; i++) {
        float4 p = pos4[i * 512 + t];           // coalesced; thread owns pts i*512+t
        px[i] = p.x; py[i] = p.y; pz[i] = p.z;
        md[i] = __builtin_inff();
    }
    float4 c0 = pos4[0];
    float cx = c0.x, cy = c0.y, cz = c0.z;
    if (t == 0) centers[0] = make_float4(cx, cy, cz, 0.f);
    for (int m = 0; m < MC - 1; m++) {
        float lv = -1.f; int li = 0;
        #pragma unroll
        for (int i = 0; i < 32; i++) {
            float d = sqdist3(px[i], py[i], pz[i], cx, cy, cz);
            float nmd = fminf(md[i], d);
            md[i] = nmd;
            bool gt = nmd > lv;                 // strict >: first (lowest i) max wins
            lv = gt ? nmd : lv;
            li = gt ? i : li;
        }
        // key: high = float bits of max-min-dist (monotone for d>=0), low = ~global_idx
        // u64 max => max distance, tie -> min global index (matches jnp.argmax first-hit)
        unsigned long long key =
            ((unsigned long long)__float_as_uint(lv) << 32) |
            (unsigned long long)(unsigned)~(unsigned)(li * 512 + t);
        #pragma unroll
        for (int off = 1; off < 64; off <<= 1) {
            unsigned long long o = __shfl_xor(key, off);
            key = (o > key) ? o : key;
        }
        if (lane == 0) s_key[m & 1][wv] = key;  // parity double-buffer kills WAR race
        __syncthreads();                        // the ONLY barrier per iteration
        key = s_key[m & 1][lane & 7];
        #pragma unroll
        for (int off = 1; off < 8; off <<= 1) {
            unsigned long long o = __shfl_xor(key, off);
            key = (o > key) ? o : key;
        }
        int idx = (int)~(unsigned)(key & 0xffffffffull);
        float4 c4 = pos4[idx];                  // wave-uniform broadcast load, L2-hot
        cx = c4.x; cy = c4.y; cz = c4.z;
        if (t == 0) centers[m + 1] = make_float4(cx, cy, cz, 0.f);
    }
}

// ---------------- kNN within radius: one wave per center ----------------
__global__ __launch_bounds__(256) void k_knn(const float4* __restrict__ pos4,
                                             const float4* __restrict__ centers,
                                             int* __restrict__ nbr_cnt,
                                             int* __restrict__ nbr_idx)
{
    __shared__ int s_ci[4][MAXC];
    __shared__ float s_cd[4][MAXC];
    const int t = threadIdx.x, lane = t & 63, wv = t >> 6;
    const int m = blockIdx.x * 4 + wv;
    float4 c = centers[m];
    int base = 0;
    for (int ch = 0; ch < NP / 64; ch++) {
        int p = ch * 64 + lane;
        float4 q = pos4[p];
        float d2 = sqdist3(q.x, q.y, q.z, c.x, c.y, c.z);
        bool pred = (d2 <= R2F);
        unsigned long long mk = __ballot(pred);
        if (pred) {
            int slot = base + (int)__popcll(mk & ((1ull << lane) - 1ull));
            if (slot < MAXC) { s_ci[wv][slot] = p; s_cd[wv][slot] = d2; }
        }
        base += (int)__popcll(mk);
    }
    int cc = min(base, MAXC);
    __syncthreads();
    if (cc <= 32) {
        if (lane < cc) nbr_idx[m * 32 + lane] = s_ci[wv][lane];
        if (lane == 0) nbr_cnt[m] = cc;
    } else {
        int ng = (cc + 63) >> 6;
        for (int g = 0; g < ng; g++) {
            int i = g * 64 + lane;
            if (i < cc) {
                float di = s_cd[wv][i]; int pi = s_ci[wv][i];
                int rank = 0;
                for (int j = 0; j < cc; j++) {
                    float dj = s_cd[wv][j]; int pj = s_ci[wv][j];
                    rank += (dj < di || (dj == di && pj < pi)) ? 1 : 0;
                }
                if (rank < 32) nbr_idx[m * 32 + rank] = pi;
            }
        }
        if (lane == 0) nbr_cnt[m] = 32;
    }
}

// ---------------- fused gather + 3-layer MLP (f16 MFMA) + masked maxpool ----------------
__global__ __launch_bounds__(256) void k_mlp(const float* __restrict__ x,
    const float4* __restrict__ pos4, const float4* __restrict__ centers,
    const int* __restrict__ nbr_cnt, const int* __restrict__ nbr_idx,
    const _Float16* __restrict__ w1t, const _Float16* __restrict__ w2t,
    const _Float16* __restrict__ w3t,
    const float* __restrict__ b1, const float* __restrict__ b2, const float* __restrict__ b3,
    float* __restrict__ out)
{
    __shared__ __align__(16) _Float16 sA[64 * 168];    // X tile: feat(128)+rel(3)+pad, K=160 used
    __shared__ __align__(16) _Float16 sW[256 * 136];   // union: W1T(128x168) / W2T(128x136) / W3T(256x136)
    __shared__ __align__(16) _Float16 sH1[64 * 136];
    __shared__ __align__(16) _Float16 sH2[64 * 136];
    __shared__ float s_pool[4][256];
    __shared__ int s_cnt[2];

    const int t = threadIdx.x, lane = t & 63, wv = t >> 6;
    const int bid = blockIdx.x;

    // ---- stage A (gather rows for 2 centers = 64 rows) ----
    {
        int r = t >> 2, tsub = t & 3;
        int g = r >> 5, s = r & 31;
        int m = bid * 2 + g;
        int cnt = nbr_cnt[m];
        if (t < 2) s_cnt[t] = nbr_cnt[bid * 2 + t];
        _Float16* row = &sA[r * 168];
        if (s < cnt) {
            int col = nbr_idx[m * 32 + s];
            const float* fx = x + (long)col * 131 + 3;
            for (int k = tsub * 32; k < tsub * 32 + 32; k++) row[k] = (_Float16)fx[k];
            if (tsub == 0) {
                float4 ctr = centers[m];
                float4 pp = pos4[col];
                row[128] = (_Float16)(pp.x - ctr.x);
                row[129] = (_Float16)(pp.y - ctr.y);
                row[130] = (_Float16)(pp.z - ctr.z);
                for (int k = 131; k < 168; k++) row[k] = (_Float16)0.f;
            }
        } else {
            for (int k = tsub * 32; k < tsub * 32 + 32; k++) row[k] = (_Float16)0.f;
            if (tsub == 0) for (int k = 128; k < 168; k++) row[k] = (_Float16)0.f;
        }
    }
    // copy W1T
    {
        const uint4* src = (const uint4*)w1t; uint4* dst = (uint4*)sW;
        for (int i = t; i < (128 * 168) / 8; i += 256) dst[i] = src[i];
    }
    __syncthreads();

    const int cl = lane & 15;
    const int kgrp = (lane >> 4) * 8;
    const int rsub = (lane >> 4) * 4;
    const int R0 = wv * 16;

    // ---- GEMM1: [64x160] @ W1T -> relu -> sH1 ----
    {
        f32x4 acc[8];
        #pragma unroll
        for (int i = 0; i < 8; i++) acc[i] = (f32x4){0.f, 0.f, 0.f, 0.f};
        #pragma unroll
        for (int ks = 0; ks < 5; ks++) {
            int kb = ks * 32 + kgrp;
            f16x8 a = *(const f16x8*)&sA[(R0 + cl) * 168 + kb];
            #pragma unroll
            for (int ct = 0; ct < 8; ct++) {
                f16x8 b = *(const f16x8*)&sW[(ct * 16 + cl) * 168 + kb];
                acc[ct] = __builtin_amdgcn_mfma_f32_16x16x32_f16(a, b, acc[ct], 0, 0, 0);
            }
        }
        #pragma unroll
        for (int ct = 0; ct < 8; ct++) {
            int c = ct * 16 + cl;
            float bb = b1[c];
            #pragma unroll
            for (int v = 0; v < 4; v++) {
                float val = fmaxf(acc[ct][v] + bb, 0.f);
                sH1[(R0 + rsub + v) * 136 + c] = (_Float16)val;
            }
        }
    }
    __syncthreads();
    // copy W2T
    {
        const uint4* src = (const uint4*)w2t; uint4* dst = (uint4*)sW;
        for (int i = t; i < (128 * 136) / 8; i += 256) dst[i] = src[i];
    }
    __syncthreads();
    // ---- GEMM2: [64x128] @ W2T -> relu -> sH2 ----
    {
        f32x4 acc[8];
        #pragma unroll
        for (int i = 0; i < 8; i++) acc[i] = (f32x4){0.f, 0.f, 0.f, 0.f};
        #pragma unroll
        for (int ks = 0; ks < 4; ks++) {
            int kb = ks * 32 + kgrp;
            f16x8 a = *(const f16x8*)&sH1[(R0 + cl) * 136 + kb];
            #pragma unroll
            for (int ct = 0; ct < 8; ct++) {
                f16x8 b = *(const f16x8*)&sW[(ct * 16 + cl) * 136 + kb];
                acc[ct] = __builtin_amdgcn_mfma_f32_16x16x32_f16(a, b, acc[ct], 0, 0, 0);
            }
        }
        #pragma unroll
        for (int ct = 0; ct < 8; ct++) {
            int c = ct * 16 + cl;
            float bb = b2[c];
            #pragma unroll
            for (int v = 0; v < 4; v++) {
                float val = fmaxf(acc[ct][v] + bb, 0.f);
                sH2[(R0 + rsub + v) * 136 + c] = (_Float16)val;
            }
        }
    }
    __syncthreads();
    // copy W3T
    {
        const uint4* src = (const uint4*)w3t; uint4* dst = (uint4*)sW;
        for (int i = t; i < (256 * 136) / 8; i += 256) dst[i] = src[i];
    }
    __syncthreads();
    // ---- GEMM3: [64x128] @ W3T (N=256) -> relu -> masked maxpool ----
    {
        f32x4 acc[16];
        #pragma unroll
        for (int i = 0; i < 16; i++) acc[i] = (f32x4){0.f, 0.f, 0.f, 0.f};
        #pragma unroll
        for (int ks = 0; ks < 4; ks++) {
            int kb = ks * 32 + kgrp;
            f16x8 a = *(const f16x8*)&sH2[(R0 + cl) * 136 + kb];
            #pragma unroll
            for (int ct = 0; ct < 16; ct++) {
                f16x8 b = *(const f16x8*)&sW[(ct * 16 + cl) * 136 + kb];
                acc[ct] = __builtin_amdgcn_mfma_f32_16x16x32_f16(a, b, acc[ct], 0, 0, 0);
            }
        }
        int cnt = s_cnt[wv >> 1];
        #pragma unroll
        for (int ct = 0; ct < 16; ct++) {
            int c = ct * 16 + cl;
            float bb = b3[c];
            float p = -__builtin_inff();
            #pragma unroll
            for (int v = 0; v < 4; v++) {
                int srow = (wv & 1) * 16 + rsub + v;   // slot within center [0,32)
                float val = fmaxf(acc[ct][v] + bb, 0.f);
                if (srow < cnt) p = fmaxf(p, val);
            }
            p = fmaxf(p, __shfl_xor(p, 16));
            p = fmaxf(p, __shfl_xor(p, 32));
            if (lane < 16) s_pool[wv][ct * 16 + lane] = p;
        }
    }
    __syncthreads();
    {
        float p0 = fmaxf(s_pool[0][t], s_pool[1][t]);
        float p1 = fmaxf(s_pool[2][t], s_pool[3][t]);
        out[(bid * 2 + 0) * 256 + t] = p0;
        out[(bid * 2 + 1) * 256 + t] = p1;
    }
}

extern "C" void kernel_launch(void* const* d_in, const int* in_sizes, int n_in,
                              void* d_out, int out_size, void* d_ws, size_t ws_size,
                              hipStream_t stream)
{
    const float* x  = (const float*)d_in[0];
    const float* W1 = (const float*)d_in[1];
    const float* b1 = (const float*)d_in[2];
    const float* W2 = (const float*)d_in[3];
    const float* b2 = (const float*)d_in[4];
    const float* W3 = (const float*)d_in[5];
    const float* b3 = (const float*)d_in[6];
    float* out = (float*)d_out;

    char* w = (char*)d_ws;
    float4* pos4    = (float4*)(w + 0);         // 262144 B
    float4* centers = (float4*)(w + 262144);    // 65536 B
    int* nbr_cnt    = (int*)(w + 327680);       // 16384 B
    int* nbr_idx    = (int*)(w + 344064);       // 524288 B
    _Float16* w1t   = (_Float16*)(w + 868352);  // 43008 B
    _Float16* w2t   = (_Float16*)(w + 911360);  // 34816 B
    _Float16* w3t   = (_Float16*)(w + 946176);  // 69632 B -> end 1015808 B

    k_prep<<<352, 256, 0, stream>>>(x, W1, W2, W3, pos4, w1t, w2t, w3t);
    k_fps<<<1, 512, 0, stream>>>(pos4, centers);
    k_knn<<<1024, 256, 0, stream>>>(pos4, centers, nbr_cnt, nbr_idx);
    k_mlp<<<2048, 256, 0, stream>>>(x, pos4, centers, nbr_cnt, nbr_idx,
                                    w1t, w2t, w3t, b1, b2, b3, out);
}